// Round 6
// baseline (1179.201 us; speedup 1.0000x reference)
//
#include <hip/hip_runtime.h>
#include <hip/hip_bf16.h>
#include <math.h>

#define V_N   100000
#define KNN   64
#define OUTW  448           // 3*128 + 64 output cols (f32)
#define ROWB  1792          // OUTW*4 bytes per out row
#define TBLOFF 1536         // byte offset of bf16 feats table inside out row (col 384)

typedef __attribute__((ext_vector_type(8))) short bf16x8;
typedef __attribute__((ext_vector_type(4))) float f32x4;

__device__ __forceinline__ unsigned short bf16bits(float f) {
    __hip_bfloat16 h = __float2bfloat16(f);
    return *(unsigned short*)&h;
}

// ---------------------------------------------------------------------------
// dense_mfma: feats = relu(in @ W + b) -> bf16 table at TBLOFF of each out row.
// ---------------------------------------------------------------------------
template<int IN>
__global__ __launch_bounds__(256) void dense_mfma_kernel(
    const float* __restrict__ in, int in_stride,
    const float* __restrict__ W, const float* __restrict__ b,
    char* __restrict__ outbase)
{
    __shared__ __hip_bfloat16 sWt[64][IN + 8];

    const int tid = threadIdx.x;
    const int v0  = blockIdx.x * 64;

#pragma unroll
    for (int e = tid; e < IN * 64; e += 256) {
        const int k = e >> 6, j = e & 63;
        sWt[j][k] = __float2bfloat16(W[e]);
    }
    __syncthreads();

    const int wv   = tid >> 6;
    const int lane = tid & 63;
    const int r    = lane & 15;
    const int ko   = (lane >> 4) * 8;

    const int arow_v = min(v0 + wv * 16 + r, V_N - 1);
    const float* arow = in + (size_t)arow_v * in_stride;

    f32x4 acc[4];
#pragma unroll
    for (int t = 0; t < 4; ++t) {
        const float bb = b[t * 16 + r];
        acc[t] = (f32x4){bb, bb, bb, bb};
    }

#pragma unroll
    for (int kb = 0; kb < IN / 32; ++kb) {
        const float4 a0 = *(const float4*)(arow + kb * 32 + ko);
        const float4 a1 = *(const float4*)(arow + kb * 32 + ko + 4);
        const float av[8] = {a0.x, a0.y, a0.z, a0.w, a1.x, a1.y, a1.z, a1.w};
        bf16x8 af;
#pragma unroll
        for (int e = 0; e < 8; ++e) af[e] = (short)bf16bits(av[e]);

#pragma unroll
        for (int t = 0; t < 4; ++t) {
            const bf16x8 bfr = *(const bf16x8*)&sWt[t * 16 + r][kb * 32 + ko];
            acc[t] = __builtin_amdgcn_mfma_f32_16x16x32_bf16(af, bfr, acc[t], 0, 0, 0);
        }
    }

#pragma unroll
    for (int t = 0; t < 4; ++t) {
#pragma unroll
        for (int reg = 0; reg < 4; ++reg) {
            const int orow = v0 + wv * 16 + (lane >> 4) * 4 + reg;
            if (orow < V_N) {
                const int j = t * 16 + r;
                *(unsigned short*)(outbase + (size_t)orow * ROWB + TBLOFF + j * 2) =
                    bf16bits(fmaxf(acc[t][reg], 0.f));
            }
        }
    }
}

// ---------------------------------------------------------------------------
// acc6: TWO rows per wave, 8 rows per block (grid = V_N/8 = 12500).
// Per wave: issue 16 gather dwordx4 (8 per row) + 2 self loads back-to-back
// into register buffers (launch_bounds(256,4) -> 128 VGPR budget so the
// compiler can keep them all in flight), then pure-VALU accumulate both rows,
// 3-level butterfly, coalesced stores. Attacks the measured latency-bound
// regime with ~2x memory-level parallelism per wave.
// ---------------------------------------------------------------------------
__global__ __launch_bounds__(256, 4) void acc6_kernel(
    const float* __restrict__ dsq,
    const int*   __restrict__ idx,
    const char*  __restrict__ tbl,
    float* __restrict__ out, int col_off)
{
    __shared__ float2 pairs[8][64];
    const int tid  = threadIdx.x;
    const int wid  = tid >> 6;
    const int lane = tid & 63;
    const int r0   = blockIdx.x * 8;

#pragma unroll
    for (int e = tid; e < 512; e += 256) {
        const int rr = e >> 6, kk = e & 63;
        const int v = r0 + rr;
        const float d  = dsq[(size_t)v * KNN + kk];
        const int   ib = idx[(size_t)v * KNN + kk] * ROWB + TBLOFF;
        pairs[rr][kk] = make_float2(__expf(-10.f * d), __int_as_float(ib));
    }
    __syncthreads();

    const int va = r0 + wid * 2;
    const int vb = va + 1;
    const int g  = lane >> 3;
    const int fq = lane & 7;
    const unsigned foff = fq * 16;

    // ---- issue phase: 16 gathers + 2 self loads, all independent ----
    float wA[8], wB[8];
    uint4 bA[8], bB[8];
#pragma unroll
    for (int it = 0; it < 8; ++it) {
        const float2 p = pairs[wid * 2][it * 8 + g];
        wA[it] = p.x;
        bA[it] = *(const uint4*)(tbl + (unsigned)__float_as_int(p.y) + foff);
    }
#pragma unroll
    for (int it = 0; it < 8; ++it) {
        const float2 p = pairs[wid * 2 + 1][it * 8 + g];
        wB[it] = p.x;
        bB[it] = *(const uint4*)(tbl + (unsigned)__float_as_int(p.y) + foff);
    }
    uint4 spA = make_uint4(0u, 0u, 0u, 0u), spB = make_uint4(0u, 0u, 0u, 0u);
    if (g < 2) {
        spA = *(const uint4*)(tbl + (size_t)va * ROWB + TBLOFF + foff);
        spB = *(const uint4*)(tbl + (size_t)vb * ROWB + TBLOFF + foff);
    }

    // ---- consume phase ----
    float sA[8] = {0,0,0,0,0,0,0,0}, mA[8] = {0,0,0,0,0,0,0,0};
    float sB[8] = {0,0,0,0,0,0,0,0}, mB[8] = {0,0,0,0,0,0,0,0};
#pragma unroll
    for (int it = 0; it < 8; ++it) {
        const unsigned uA[4] = {bA[it].x, bA[it].y, bA[it].z, bA[it].w};
        const float wa = wA[it];
#pragma unroll
        for (int q = 0; q < 4; ++q) {
            const float vlo = wa * __uint_as_float(uA[q] << 16);
            const float vhi = wa * __uint_as_float(uA[q] & 0xffff0000u);
            sA[2*q] += vlo; sA[2*q+1] += vhi;
            mA[2*q] = fmaxf(mA[2*q], vlo); mA[2*q+1] = fmaxf(mA[2*q+1], vhi);
        }
    }
#pragma unroll
    for (int it = 0; it < 8; ++it) {
        const unsigned uB[4] = {bB[it].x, bB[it].y, bB[it].z, bB[it].w};
        const float wb = wB[it];
#pragma unroll
        for (int q = 0; q < 4; ++q) {
            const float vlo = wb * __uint_as_float(uB[q] << 16);
            const float vhi = wb * __uint_as_float(uB[q] & 0xffff0000u);
            sB[2*q] += vlo; sB[2*q+1] += vhi;
            mB[2*q] = fmaxf(mB[2*q], vlo); mB[2*q+1] = fmaxf(mB[2*q+1], vhi);
        }
    }

    // butterfly over neighbor groups (lane bits 3,4,5), both rows
#pragma unroll
    for (int msk = 8; msk <= 32; msk <<= 1) {
#pragma unroll
        for (int e = 0; e < 8; ++e) {
            sA[e] += __shfl_xor(sA[e], msk);
            mA[e] = fmaxf(mA[e], __shfl_xor(mA[e], msk));
            sB[e] += __shfl_xor(sB[e], msk);
            mB[e] = fmaxf(mB[e], __shfl_xor(mB[e], msk));
        }
    }

    if (g < 2) {
#pragma unroll
        for (int row = 0; row < 2; ++row) {
            const int v = row ? vb : va;
            const uint4 sp = row ? spB : spA;
            const float* s = row ? sB : sA;
            const float* m = row ? mB : mA;
            const unsigned su[4] = {sp.x, sp.y, sp.z, sp.w};
            float e[8];
#pragma unroll
            for (int q = 0; q < 4; ++q) {
                e[2*q]   = __uint_as_float(su[q] << 16);
                e[2*q+1] = __uint_as_float(su[q] & 0xffff0000u);
            }
            float rr[8];
            float* dst;
            if (g == 0) {
#pragma unroll
                for (int k = 0; k < 8; ++k) rr[k] = s[k] * (1.f / 64.f) - e[k];
                dst = &out[(size_t)v * OUTW + col_off + fq * 8];
            } else {
#pragma unroll
                for (int k = 0; k < 8; ++k) rr[k] = m[k] - e[k];
                dst = &out[(size_t)v * OUTW + col_off + 64 + fq * 8];
            }
            *(float4*)dst       = make_float4(rr[0], rr[1], rr[2], rr[3]);
            *(float4*)(dst + 4) = make_float4(rr[4], rr[5], rr[6], rr[7]);
        }
    }
}

// ---------------------------------------------------------------------------
// copyx: overwrite the table region (cols 384..448) with x, float4-vectorized.
// ---------------------------------------------------------------------------
__global__ __launch_bounds__(256) void copyx_kernel(
    const float* __restrict__ x, float* __restrict__ out)
{
    const int t = blockIdx.x * blockDim.x + threadIdx.x;
    if (t < V_N * 16) {
        const int v = t >> 4, f4 = (t & 15) * 4;
        *(float4*)&out[(size_t)v * OUTW + 384 + f4] =
            *(const float4*)&x[(size_t)v * 64 + f4];
    }
}

extern "C" void kernel_launch(void* const* d_in, const int* in_sizes, int n_in,
                              void* d_out, int out_size, void* d_ws, size_t ws_size,
                              hipStream_t stream)
{
    const float* x   = (const float*)d_in[0];
    const float* dsq = (const float*)d_in[1];
    const int*   idx = (const int*)  d_in[2];
    const float* W0  = (const float*)d_in[3];
    const float* b0  = (const float*)d_in[4];
    const float* W1  = (const float*)d_in[5];
    const float* b1  = (const float*)d_in[6];
    const float* W2  = (const float*)d_in[7];
    const float* b2  = (const float*)d_in[8];
    float* out = (float*)d_out;
    char*  outc = (char*)d_out;

    const dim3 blk(256);
    const int nb_dense = (V_N + 63) / 64;   // 1563
    const int nb_acc   = V_N / 8;           // 12500 (exact)

    dense_mfma_kernel<64><<<nb_dense, blk, 0, stream>>>(x, 64, W0, b0, outc);
    acc6_kernel<<<nb_acc, blk, 0, stream>>>(dsq, idx, outc, out, 0);
    dense_mfma_kernel<128><<<nb_dense, blk, 0, stream>>>(out + 0, OUTW, W1, b1, outc);
    acc6_kernel<<<nb_acc, blk, 0, stream>>>(dsq, idx, outc, out, 128);
    dense_mfma_kernel<128><<<nb_dense, blk, 0, stream>>>(out + 128, OUTW, W2, b2, outc);
    acc6_kernel<<<nb_acc, blk, 0, stream>>>(dsq, idx, outc, out, 256);
    copyx_kernel<<<(V_N * 16 + 255) / 256, blk, 0, stream>>>(x, out);
}

// Round 8
// 364.765 us; speedup vs baseline: 3.2328x; 3.2328x over previous
//
#include <hip/hip_runtime.h>
#include <hip/hip_bf16.h>
#include <math.h>

#define V_N   100000
#define KNN   64
#define OUTW  448           // 3*128 + 64 output cols (f32)
#define ROWB  1792          // OUTW*4 bytes per out row
#define TBLOFF 1536         // byte offset of bf16 feats table inside out row (col 384)

typedef __attribute__((ext_vector_type(8))) short bf16x8;
typedef __attribute__((ext_vector_type(4))) float f32x4;
typedef __attribute__((ext_vector_type(4))) unsigned int u32x4;

__device__ __forceinline__ unsigned short bf16bits(float f) {
    __hip_bfloat16 h = __float2bfloat16(f);
    return *(unsigned short*)&h;
}

// ---------------------------------------------------------------------------
// dense_mfma: feats = relu(in @ W + b) -> bf16 table at TBLOFF of each out row.
// Streaming input reads are nontemporal (read-once) to spare L2 for the table.
// ---------------------------------------------------------------------------
template<int IN>
__global__ __launch_bounds__(256) void dense_mfma_kernel(
    const float* __restrict__ in, int in_stride,
    const float* __restrict__ W, const float* __restrict__ b,
    char* __restrict__ outbase)
{
    __shared__ __hip_bfloat16 sWt[64][IN + 8];

    const int tid = threadIdx.x;
    const int v0  = blockIdx.x * 64;

#pragma unroll
    for (int e = tid; e < IN * 64; e += 256) {
        const int k = e >> 6, j = e & 63;
        sWt[j][k] = __float2bfloat16(W[e]);
    }
    __syncthreads();

    const int wv   = tid >> 6;
    const int lane = tid & 63;
    const int r    = lane & 15;
    const int ko   = (lane >> 4) * 8;

    const int arow_v = min(v0 + wv * 16 + r, V_N - 1);
    const float* arow = in + (size_t)arow_v * in_stride;

    f32x4 acc[4];
#pragma unroll
    for (int t = 0; t < 4; ++t) {
        const float bb = b[t * 16 + r];
        acc[t] = (f32x4){bb, bb, bb, bb};
    }

#pragma unroll
    for (int kb = 0; kb < IN / 32; ++kb) {
        const f32x4 a0 = __builtin_nontemporal_load((const f32x4*)(arow + kb * 32 + ko));
        const f32x4 a1 = __builtin_nontemporal_load((const f32x4*)(arow + kb * 32 + ko + 4));
        const float av[8] = {a0[0], a0[1], a0[2], a0[3], a1[0], a1[1], a1[2], a1[3]};
        bf16x8 af;
#pragma unroll
        for (int e = 0; e < 8; ++e) af[e] = (short)bf16bits(av[e]);

#pragma unroll
        for (int t = 0; t < 4; ++t) {
            const bf16x8 bfr = *(const bf16x8*)&sWt[t * 16 + r][kb * 32 + ko];
            acc[t] = __builtin_amdgcn_mfma_f32_16x16x32_bf16(af, bfr, acc[t], 0, 0, 0);
        }
    }

    // table writes stay cached (gathered next) — NOT nontemporal
#pragma unroll
    for (int t = 0; t < 4; ++t) {
#pragma unroll
        for (int reg = 0; reg < 4; ++reg) {
            const int orow = v0 + wv * 16 + (lane >> 4) * 4 + reg;
            if (orow < V_N) {
                const int j = t * 16 + r;
                *(unsigned short*)(outbase + (size_t)orow * ROWB + TBLOFF + j * 2) =
                    bf16bits(fmaxf(acc[t][reg], 0.f));
            }
        }
    }
}

// ---------------------------------------------------------------------------
// acc7: acc5 structure (proven 102 us) + nontemporal streaming traffic.
// One wave per row v; 8 lanes x 16B cover one 128B table row; 8 rows per
// iteration; (w, base) pairs staged in LDS. Gather loads stay CACHED;
// dsq/idx reads and out stores are nontemporal so they don't evict the
// 12.8 MB table from the 4 MB per-XCD L2s.
// ---------------------------------------------------------------------------
__global__ __launch_bounds__(256) void acc7_kernel(
    const float* __restrict__ dsq,
    const int*   __restrict__ idx,
    const char*  __restrict__ tbl,
    float* __restrict__ out, int col_off)
{
    __shared__ float2 pairs[4][64];
    const int tid  = threadIdx.x;
    const int wid  = tid >> 6;
    const int lane = tid & 63;
    const int v    = blockIdx.x * 4 + wid;

    const float d  = __builtin_nontemporal_load(&dsq[(size_t)v * KNN + lane]);
    const int   ib = __builtin_nontemporal_load(&idx[(size_t)v * KNN + lane]) * ROWB + TBLOFF;
    pairs[wid][lane] = make_float2(__expf(-10.f * d), __int_as_float(ib));
    __syncthreads();

    const int g  = lane >> 3;
    const int fq = lane & 7;
    const unsigned foff = fq * 16;

    // ---- issue phase ----
    float wk[8];
    u32x4 buf[8];
#pragma unroll
    for (int it = 0; it < 8; ++it) {
        const float2 pw = pairs[wid][it * 8 + g];
        wk[it] = pw.x;
        buf[it] = *(const u32x4*)(tbl + (unsigned)__float_as_int(pw.y) + foff);
    }
    u32x4 sp = (u32x4){0u, 0u, 0u, 0u};
    if (g < 2) sp = *(const u32x4*)(tbl + (size_t)v * ROWB + TBLOFF + foff);

    // ---- consume phase ----
    float s[8] = {0.f, 0.f, 0.f, 0.f, 0.f, 0.f, 0.f, 0.f};
    float m[8] = {0.f, 0.f, 0.f, 0.f, 0.f, 0.f, 0.f, 0.f};
#pragma unroll
    for (int it = 0; it < 8; ++it) {
        const unsigned u[4] = {buf[it][0], buf[it][1], buf[it][2], buf[it][3]};
        const float w = wk[it];
#pragma unroll
        for (int q = 0; q < 4; ++q) {
            const float vlo = w * __uint_as_float(u[q] << 16);
            const float vhi = w * __uint_as_float(u[q] & 0xffff0000u);
            s[2 * q]     += vlo;  s[2 * q + 1] += vhi;
            m[2 * q]     = fmaxf(m[2 * q], vlo);
            m[2 * q + 1] = fmaxf(m[2 * q + 1], vhi);
        }
    }

    // butterfly over the 8 neighbor groups (lane bits 3,4,5)
#pragma unroll
    for (int msk = 8; msk <= 32; msk <<= 1) {
#pragma unroll
        for (int e = 0; e < 8; ++e) {
            s[e] += __shfl_xor(s[e], msk);
            m[e] = fmaxf(m[e], __shfl_xor(m[e], msk));
        }
    }

    if (g < 2) {
        const unsigned su[4] = {sp[0], sp[1], sp[2], sp[3]};
        float e[8];
#pragma unroll
        for (int q = 0; q < 4; ++q) {
            e[2 * q]     = __uint_as_float(su[q] << 16);
            e[2 * q + 1] = __uint_as_float(su[q] & 0xffff0000u);
        }
        float* dst;
        float r[8];
        if (g == 0) {
#pragma unroll
            for (int k = 0; k < 8; ++k) r[k] = s[k] * (1.f / 64.f) - e[k];
            dst = &out[(size_t)v * OUTW + col_off + fq * 8];
        } else {
#pragma unroll
            for (int k = 0; k < 8; ++k) r[k] = m[k] - e[k];
            dst = &out[(size_t)v * OUTW + col_off + 64 + fq * 8];
        }
        __builtin_nontemporal_store((f32x4){r[0], r[1], r[2], r[3]}, (f32x4*)dst);
        __builtin_nontemporal_store((f32x4){r[4], r[5], r[6], r[7]}, (f32x4*)(dst + 4));
    }
}

// ---------------------------------------------------------------------------
// copyx: overwrite the table region (cols 384..448) with x, all nontemporal.
// ---------------------------------------------------------------------------
__global__ __launch_bounds__(256) void copyx_kernel(
    const float* __restrict__ x, float* __restrict__ out)
{
    const int t = blockIdx.x * blockDim.x + threadIdx.x;
    if (t < V_N * 16) {
        const int v = t >> 4, f4 = (t & 15) * 4;
        const f32x4 val = __builtin_nontemporal_load((const f32x4*)&x[(size_t)v * 64 + f4]);
        __builtin_nontemporal_store(val, (f32x4*)&out[(size_t)v * OUTW + 384 + f4]);
    }
}

extern "C" void kernel_launch(void* const* d_in, const int* in_sizes, int n_in,
                              void* d_out, int out_size, void* d_ws, size_t ws_size,
                              hipStream_t stream)
{
    const float* x   = (const float*)d_in[0];
    const float* dsq = (const float*)d_in[1];
    const int*   idx = (const int*)  d_in[2];
    const float* W0  = (const float*)d_in[3];
    const float* b0  = (const float*)d_in[4];
    const float* W1  = (const float*)d_in[5];
    const float* b1  = (const float*)d_in[6];
    const float* W2  = (const float*)d_in[7];
    const float* b2  = (const float*)d_in[8];
    float* out = (float*)d_out;
    char*  outc = (char*)d_out;

    const dim3 blk(256);
    const int nb_dense = (V_N + 63) / 64;   // 1563
    const int nb_acc   = V_N / 4;           // 25000 (exact)

    dense_mfma_kernel<64><<<nb_dense, blk, 0, stream>>>(x, 64, W0, b0, outc);
    acc7_kernel<<<nb_acc, blk, 0, stream>>>(dsq, idx, outc, out, 0);
    dense_mfma_kernel<128><<<nb_dense, blk, 0, stream>>>(out + 0, OUTW, W1, b1, outc);
    acc7_kernel<<<nb_acc, blk, 0, stream>>>(dsq, idx, outc, out, 128);
    dense_mfma_kernel<128><<<nb_dense, blk, 0, stream>>>(out + 128, OUTW, W2, b2, outc);
    acc7_kernel<<<nb_acc, blk, 0, stream>>>(dsq, idx, outc, out, 256);
    copyx_kernel<<<(V_N * 16 + 255) / 256, blk, 0, stream>>>(x, out);
}

// Round 9
// 358.505 us; speedup vs baseline: 3.2892x; 1.0175x over previous
//
#include <hip/hip_runtime.h>
#include <hip/hip_bf16.h>
#include <math.h>

#define V_N   100000
#define KNN   64
#define OUTW  448           // 3*128 + 64 output cols (f32)
#define ROWB  1792          // OUTW*4 bytes per out row
#define TBLOFF 1536         // byte offset of bf16 feats table inside out row (col 384)

typedef __attribute__((ext_vector_type(8))) short bf16x8;
typedef __attribute__((ext_vector_type(4))) float f32x4;

__device__ __forceinline__ unsigned short bf16bits(float f) {
    __hip_bfloat16 h = __float2bfloat16(f);
    return *(unsigned short*)&h;
}

// ---------------------------------------------------------------------------
// dense_mfma: feats = relu(in @ W + b) -> bf16 table at TBLOFF of each out row.
// Block = 256 threads = 4 waves; each wave does a 16-row x 64-col tile via
// mfma_f32_16x16x32_bf16.
// ---------------------------------------------------------------------------
template<int IN>
__global__ __launch_bounds__(256) void dense_mfma_kernel(
    const float* __restrict__ in, int in_stride,
    const float* __restrict__ W, const float* __restrict__ b,
    char* __restrict__ outbase)
{
    __shared__ __hip_bfloat16 sWt[64][IN + 8];

    const int tid = threadIdx.x;
    const int v0  = blockIdx.x * 64;

#pragma unroll
    for (int e = tid; e < IN * 64; e += 256) {
        const int k = e >> 6, j = e & 63;
        sWt[j][k] = __float2bfloat16(W[e]);
    }
    __syncthreads();

    const int wv   = tid >> 6;
    const int lane = tid & 63;
    const int r    = lane & 15;
    const int ko   = (lane >> 4) * 8;

    const int arow_v = min(v0 + wv * 16 + r, V_N - 1);
    const float* arow = in + (size_t)arow_v * in_stride;

    f32x4 acc[4];
#pragma unroll
    for (int t = 0; t < 4; ++t) {
        const float bb = b[t * 16 + r];
        acc[t] = (f32x4){bb, bb, bb, bb};
    }

#pragma unroll
    for (int kb = 0; kb < IN / 32; ++kb) {
        const float4 a0 = *(const float4*)(arow + kb * 32 + ko);
        const float4 a1 = *(const float4*)(arow + kb * 32 + ko + 4);
        const float av[8] = {a0.x, a0.y, a0.z, a0.w, a1.x, a1.y, a1.z, a1.w};
        bf16x8 af;
#pragma unroll
        for (int e = 0; e < 8; ++e) af[e] = (short)bf16bits(av[e]);

#pragma unroll
        for (int t = 0; t < 4; ++t) {
            const bf16x8 bfr = *(const bf16x8*)&sWt[t * 16 + r][kb * 32 + ko];
            acc[t] = __builtin_amdgcn_mfma_f32_16x16x32_bf16(af, bfr, acc[t], 0, 0, 0);
        }
    }

#pragma unroll
    for (int t = 0; t < 4; ++t) {
#pragma unroll
        for (int reg = 0; reg < 4; ++reg) {
            const int orow = v0 + wv * 16 + (lane >> 4) * 4 + reg;
            if (orow < V_N) {
                const int j = t * 16 + r;
                *(unsigned short*)(outbase + (size_t)orow * ROWB + TBLOFF + j * 2) =
                    bf16bits(fmaxf(acc[t][reg], 0.f));
            }
        }
    }
}

// ---------------------------------------------------------------------------
// acc5: one wave per row v. 8 lanes x 16B cover one 128B (one-cache-line)
// bf16 table row; 8 rows gathered per iteration; (w, base) pairs staged in
// LDS (1 conflict-free ds_read_b64/iter). Two-phase: issue all gathers,
// then pure-VALU accumulate; 3-level butterfly; coalesced float4 stores.
// Measured at the random-gather service-rate floor (~102 us; FETCH 318 MB
// @ ~3.1 TB/s L2-miss path) across 4 structural variants.
// ---------------------------------------------------------------------------
__global__ __launch_bounds__(256) void acc5_kernel(
    const float* __restrict__ dsq,
    const int*   __restrict__ idx,
    const char*  __restrict__ tbl,
    float* __restrict__ out, int col_off)
{
    __shared__ float2 pairs[4][64];
    const int tid  = threadIdx.x;
    const int wid  = tid >> 6;
    const int lane = tid & 63;
    const int v    = blockIdx.x * 4 + wid;

    const float d  = dsq[(size_t)v * KNN + lane];
    const int   ib = idx[(size_t)v * KNN + lane] * ROWB + TBLOFF;
    pairs[wid][lane] = make_float2(__expf(-10.f * d), __int_as_float(ib));
    __syncthreads();

    const int g  = lane >> 3;
    const int fq = lane & 7;
    const unsigned foff = fq * 16;

    // ---- issue phase ----
    float wk[8];
    uint4 buf[8];
#pragma unroll
    for (int it = 0; it < 8; ++it) {
        const float2 pw = pairs[wid][it * 8 + g];
        wk[it] = pw.x;
        buf[it] = *(const uint4*)(tbl + (unsigned)__float_as_int(pw.y) + foff);
    }
    uint4 sp = make_uint4(0u, 0u, 0u, 0u);
    if (g < 2) sp = *(const uint4*)(tbl + (size_t)v * ROWB + TBLOFF + foff);

    // ---- consume phase ----
    float s[8] = {0.f, 0.f, 0.f, 0.f, 0.f, 0.f, 0.f, 0.f};
    float m[8] = {0.f, 0.f, 0.f, 0.f, 0.f, 0.f, 0.f, 0.f};
#pragma unroll
    for (int it = 0; it < 8; ++it) {
        const unsigned u[4] = {buf[it].x, buf[it].y, buf[it].z, buf[it].w};
        const float w = wk[it];
#pragma unroll
        for (int q = 0; q < 4; ++q) {
            const float vlo = w * __uint_as_float(u[q] << 16);
            const float vhi = w * __uint_as_float(u[q] & 0xffff0000u);
            s[2 * q]     += vlo;  s[2 * q + 1] += vhi;
            m[2 * q]     = fmaxf(m[2 * q], vlo);
            m[2 * q + 1] = fmaxf(m[2 * q + 1], vhi);
        }
    }

    // butterfly over the 8 neighbor groups (lane bits 3,4,5)
#pragma unroll
    for (int msk = 8; msk <= 32; msk <<= 1) {
#pragma unroll
        for (int e = 0; e < 8; ++e) {
            s[e] += __shfl_xor(s[e], msk);
            m[e] = fmaxf(m[e], __shfl_xor(m[e], msk));
        }
    }

    if (g < 2) {
        const unsigned su[4] = {sp.x, sp.y, sp.z, sp.w};
        float e[8];
#pragma unroll
        for (int q = 0; q < 4; ++q) {
            e[2 * q]     = __uint_as_float(su[q] << 16);
            e[2 * q + 1] = __uint_as_float(su[q] & 0xffff0000u);
        }
        float* dst;
        float r[8];
        if (g == 0) {
#pragma unroll
            for (int k = 0; k < 8; ++k) r[k] = s[k] * (1.f / 64.f) - e[k];
            dst = &out[(size_t)v * OUTW + col_off + fq * 8];
        } else {
#pragma unroll
            for (int k = 0; k < 8; ++k) r[k] = m[k] - e[k];
            dst = &out[(size_t)v * OUTW + col_off + 64 + fq * 8];
        }
        *(float4*)dst       = make_float4(r[0], r[1], r[2], r[3]);
        *(float4*)(dst + 4) = make_float4(r[4], r[5], r[6], r[7]);
    }
}

// ---------------------------------------------------------------------------
// copyx: overwrite the table region (cols 384..448) with x, float4-vectorized.
// ---------------------------------------------------------------------------
__global__ __launch_bounds__(256) void copyx_kernel(
    const float* __restrict__ x, float* __restrict__ out)
{
    const int t = blockIdx.x * blockDim.x + threadIdx.x;
    if (t < V_N * 16) {
        const int v = t >> 4, f4 = (t & 15) * 4;
        *(float4*)&out[(size_t)v * OUTW + 384 + f4] =
            *(const float4*)&x[(size_t)v * 64 + f4];
    }
}

extern "C" void kernel_launch(void* const* d_in, const int* in_sizes, int n_in,
                              void* d_out, int out_size, void* d_ws, size_t ws_size,
                              hipStream_t stream)
{
    const float* x   = (const float*)d_in[0];
    const float* dsq = (const float*)d_in[1];
    const int*   idx = (const int*)  d_in[2];
    const float* W0  = (const float*)d_in[3];
    const float* b0  = (const float*)d_in[4];
    const float* W1  = (const float*)d_in[5];
    const float* b1  = (const float*)d_in[6];
    const float* W2  = (const float*)d_in[7];
    const float* b2  = (const float*)d_in[8];
    float* out = (float*)d_out;
    char*  outc = (char*)d_out;

    const dim3 blk(256);
    const int nb_dense = (V_N + 63) / 64;   // 1563
    const int nb_acc   = V_N / 4;           // 25000 (exact)

    dense_mfma_kernel<64><<<nb_dense, blk, 0, stream>>>(x, 64, W0, b0, outc);
    acc5_kernel<<<nb_acc, blk, 0, stream>>>(dsq, idx, outc, out, 0);
    dense_mfma_kernel<128><<<nb_dense, blk, 0, stream>>>(out + 0, OUTW, W1, b1, outc);
    acc5_kernel<<<nb_acc, blk, 0, stream>>>(dsq, idx, outc, out, 128);
    dense_mfma_kernel<128><<<nb_dense, blk, 0, stream>>>(out + 128, OUTW, W2, b2, outc);
    acc5_kernel<<<nb_acc, blk, 0, stream>>>(dsq, idx, outc, out, 256);
    copyx_kernel<<<(V_N * 16 + 255) / 256, blk, 0, stream>>>(x, out);
}

// Round 10
// 344.576 us; speedup vs baseline: 3.4222x; 1.0404x over previous
//
#include <hip/hip_runtime.h>
#include <hip/hip_bf16.h>
#include <math.h>

#define V_N   100000
#define KNN   64
#define OUTW  448           // 3*128 + 64 output cols (f32)
#define ROWB  1792          // OUTW*4 bytes per out row
#define TBLOFF 1536         // byte offset of embedded table (fallback path)

typedef __attribute__((ext_vector_type(8))) short bf16x8;
typedef __attribute__((ext_vector_type(4))) float f32x4;

__device__ __forceinline__ unsigned short bf16bits(float f) {
    __hip_bfloat16 h = __float2bfloat16(f);
    return *(unsigned short*)&h;
}

// ---------------------------------------------------------------------------
// dense_mfma: feats = relu(in @ W + b) -> bf16 table rows of 128 B at
// tblbase + v*rowb. Block = 256 threads = 4 waves; each wave does a
// 16-row x 64-col tile via mfma_f32_16x16x32_bf16.
// ---------------------------------------------------------------------------
template<int IN>
__global__ __launch_bounds__(256) void dense_mfma_kernel(
    const float* __restrict__ in, int in_stride,
    const float* __restrict__ W, const float* __restrict__ b,
    char* __restrict__ tblbase, int rowb)
{
    __shared__ __hip_bfloat16 sWt[64][IN + 8];

    const int tid = threadIdx.x;
    const int v0  = blockIdx.x * 64;

#pragma unroll
    for (int e = tid; e < IN * 64; e += 256) {
        const int k = e >> 6, j = e & 63;
        sWt[j][k] = __float2bfloat16(W[e]);
    }
    __syncthreads();

    const int wv   = tid >> 6;
    const int lane = tid & 63;
    const int r    = lane & 15;
    const int ko   = (lane >> 4) * 8;

    const int arow_v = min(v0 + wv * 16 + r, V_N - 1);
    const float* arow = in + (size_t)arow_v * in_stride;

    f32x4 acc[4];
#pragma unroll
    for (int t = 0; t < 4; ++t) {
        const float bb = b[t * 16 + r];
        acc[t] = (f32x4){bb, bb, bb, bb};
    }

#pragma unroll
    for (int kb = 0; kb < IN / 32; ++kb) {
        const float4 a0 = *(const float4*)(arow + kb * 32 + ko);
        const float4 a1 = *(const float4*)(arow + kb * 32 + ko + 4);
        const float av[8] = {a0.x, a0.y, a0.z, a0.w, a1.x, a1.y, a1.z, a1.w};
        bf16x8 af;
#pragma unroll
        for (int e = 0; e < 8; ++e) af[e] = (short)bf16bits(av[e]);

#pragma unroll
        for (int t = 0; t < 4; ++t) {
            const bf16x8 bfr = *(const bf16x8*)&sWt[t * 16 + r][kb * 32 + ko];
            acc[t] = __builtin_amdgcn_mfma_f32_16x16x32_bf16(af, bfr, acc[t], 0, 0, 0);
        }
    }

#pragma unroll
    for (int t = 0; t < 4; ++t) {
#pragma unroll
        for (int reg = 0; reg < 4; ++reg) {
            const int orow = v0 + wv * 16 + (lane >> 4) * 4 + reg;
            if (orow < V_N) {
                const int j = t * 16 + r;
                *(unsigned short*)(tblbase + (size_t)orow * rowb + j * 2) =
                    bf16bits(fmaxf(acc[t][reg], 0.f));
            }
        }
    }
}

// ---------------------------------------------------------------------------
// acc5: one wave per row v. 8 lanes x 16B cover one 128B (one-cache-line)
// bf16 table row; 8 rows gathered per iteration; (w, base) pairs staged in
// LDS. Two-phase issue/consume; 3-level butterfly; coalesced float4 stores.
// ---------------------------------------------------------------------------
__global__ __launch_bounds__(256) void acc5_kernel(
    const float* __restrict__ dsq,
    const int*   __restrict__ idx,
    const char*  __restrict__ tbl, int rowb,
    float* __restrict__ out, int col_off)
{
    __shared__ float2 pairs[4][64];
    const int tid  = threadIdx.x;
    const int wid  = tid >> 6;
    const int lane = tid & 63;
    const int v    = blockIdx.x * 4 + wid;

    const float d  = dsq[(size_t)v * KNN + lane];
    const int   ib = idx[(size_t)v * KNN + lane] * rowb;
    pairs[wid][lane] = make_float2(__expf(-10.f * d), __int_as_float(ib));
    __syncthreads();

    const int g  = lane >> 3;
    const int fq = lane & 7;
    const unsigned foff = fq * 16;

    // ---- issue phase ----
    float wk[8];
    uint4 buf[8];
#pragma unroll
    for (int it = 0; it < 8; ++it) {
        const float2 pw = pairs[wid][it * 8 + g];
        wk[it] = pw.x;
        buf[it] = *(const uint4*)(tbl + (unsigned)__float_as_int(pw.y) + foff);
    }
    uint4 sp = make_uint4(0u, 0u, 0u, 0u);
    if (g < 2) sp = *(const uint4*)(tbl + (size_t)v * rowb + foff);

    // ---- consume phase ----
    float s[8] = {0.f, 0.f, 0.f, 0.f, 0.f, 0.f, 0.f, 0.f};
    float m[8] = {0.f, 0.f, 0.f, 0.f, 0.f, 0.f, 0.f, 0.f};
#pragma unroll
    for (int it = 0; it < 8; ++it) {
        const unsigned u[4] = {buf[it].x, buf[it].y, buf[it].z, buf[it].w};
        const float w = wk[it];
#pragma unroll
        for (int q = 0; q < 4; ++q) {
            const float vlo = w * __uint_as_float(u[q] << 16);
            const float vhi = w * __uint_as_float(u[q] & 0xffff0000u);
            s[2 * q]     += vlo;  s[2 * q + 1] += vhi;
            m[2 * q]     = fmaxf(m[2 * q], vlo);
            m[2 * q + 1] = fmaxf(m[2 * q + 1], vhi);
        }
    }

    // butterfly over the 8 neighbor groups (lane bits 3,4,5)
#pragma unroll
    for (int msk = 8; msk <= 32; msk <<= 1) {
#pragma unroll
        for (int e = 0; e < 8; ++e) {
            s[e] += __shfl_xor(s[e], msk);
            m[e] = fmaxf(m[e], __shfl_xor(m[e], msk));
        }
    }

    if (g < 2) {
        const unsigned su[4] = {sp.x, sp.y, sp.z, sp.w};
        float e[8];
#pragma unroll
        for (int q = 0; q < 4; ++q) {
            e[2 * q]     = __uint_as_float(su[q] << 16);
            e[2 * q + 1] = __uint_as_float(su[q] & 0xffff0000u);
        }
        float* dst;
        float r[8];
        if (g == 0) {
#pragma unroll
            for (int k = 0; k < 8; ++k) r[k] = s[k] * (1.f / 64.f) - e[k];
            dst = &out[(size_t)v * OUTW + col_off + fq * 8];
        } else {
#pragma unroll
            for (int k = 0; k < 8; ++k) r[k] = m[k] - e[k];
            dst = &out[(size_t)v * OUTW + col_off + 64 + fq * 8];
        }
        *(float4*)dst       = make_float4(r[0], r[1], r[2], r[3]);
        *(float4*)(dst + 4) = make_float4(r[4], r[5], r[6], r[7]);
    }
}

// ---------------------------------------------------------------------------
// copyx: fill out cols [384,448) with x, float4-vectorized.
// ---------------------------------------------------------------------------
__global__ __launch_bounds__(256) void copyx_kernel(
    const float* __restrict__ x, float* __restrict__ out)
{
    const int t = blockIdx.x * blockDim.x + threadIdx.x;
    if (t < V_N * 16) {
        const int v = t >> 4, f4 = (t & 15) * 4;
        *(float4*)&out[(size_t)v * OUTW + 384 + f4] =
            *(const float4*)&x[(size_t)v * 64 + f4];
    }
}

extern "C" void kernel_launch(void* const* d_in, const int* in_sizes, int n_in,
                              void* d_out, int out_size, void* d_ws, size_t ws_size,
                              hipStream_t stream)
{
    const float* x   = (const float*)d_in[0];
    const float* dsq = (const float*)d_in[1];
    const int*   idx = (const int*)  d_in[2];
    const float* W0  = (const float*)d_in[3];
    const float* b0  = (const float*)d_in[4];
    const float* W1  = (const float*)d_in[5];
    const float* b1  = (const float*)d_in[6];
    const float* W2  = (const float*)d_in[7];
    const float* b2  = (const float*)d_in[8];
    float* out = (float*)d_out;

    // Compact dense table in d_ws (stride 128 B = 1 cache line, no L2 set
    // aliasing); fall back to the embedded-in-out layout if ws is too small.
    const bool use_ws = (ws_size >= (size_t)V_N * 128);
    char*     tbl  = use_ws ? (char*)d_ws : ((char*)d_out + TBLOFF);
    const int rowb = use_ws ? 128 : ROWB;

    const dim3 blk(256);
    const int nb_dense = (V_N + 63) / 64;   // 1563
    const int nb_acc   = V_N / 4;           // 25000 (exact)

    dense_mfma_kernel<64><<<nb_dense, blk, 0, stream>>>(x, 64, W0, b0, tbl, rowb);
    acc5_kernel<<<nb_acc, blk, 0, stream>>>(dsq, idx, tbl, rowb, out, 0);
    dense_mfma_kernel<128><<<nb_dense, blk, 0, stream>>>(out + 0, OUTW, W1, b1, tbl, rowb);
    acc5_kernel<<<nb_acc, blk, 0, stream>>>(dsq, idx, tbl, rowb, out, 128);
    dense_mfma_kernel<128><<<nb_dense, blk, 0, stream>>>(out + 128, OUTW, W2, b2, tbl, rowb);
    acc5_kernel<<<nb_acc, blk, 0, stream>>>(dsq, idx, tbl, rowb, out, 256);
    copyx_kernel<<<(V_N * 16 + 255) / 256, blk, 0, stream>>>(x, out);
}